// Round 1
// baseline (2325.602 us; speedup 1.0000x reference)
//
#include <hip/hip_runtime.h>
#include <hip/hip_bf16.h>

#define CH    192
#define NB    4
#define NHH   256
#define NWW   256
#define NPOS  (NB*NHH*NWW)   // 262144
#define HEADS 8
#define DH    24
#define WIN   16

__device__ __forceinline__ void fma4(float4& d, float a, const float4 b) {
    d.x += a * b.x; d.y += a * b.y; d.z += a * b.z; d.w += a * b.w;
}

// ---------------------------------------------------------------------------
// K1/K4: optional LayerNorm + pointwise (1x1) GEMM.
//   y[p][n] = sum_k LN(x)[p][k] * w[n][k]
// Tile: 64 positions x all 192 outputs, BK=16.
// LDS: Atr[192][68] (xn transposed, pad 68 -> b128-aligned, ~2-way banks)
//      Bs[16][192]  (weight k-slab)
// Inner loop per kk: 1 b128 A-read + 3 b128 B-reads + 48 v_fma_f32.
// ---------------------------------------------------------------------------
__global__ __launch_bounds__(256) void ln_gemm_kernel(
    const float* __restrict__ xin, const float* __restrict__ lng, const float* __restrict__ lnb,
    const float* __restrict__ w_a, const float* __restrict__ w_b, const float* __restrict__ w_c,
    float* __restrict__ y_a, float* __restrict__ y_b, float* __restrict__ y_c,
    int do_ln)
{
    __shared__ float Atr[CH][68];   // [k][m], 52,224 B
    __shared__ float Bs[16][CH];    // [kk][n], 12,288 B   (total 64,512 B)
    const float* wmat = (blockIdx.z == 0) ? w_a : (blockIdx.z == 1) ? w_b : w_c;
    float*       yout = (blockIdx.z == 0) ? y_a : (blockIdx.z == 1) ? y_b : y_c;
    const int t  = threadIdx.x;
    const int p0 = blockIdx.x * 64;

    // ---- stage A: load 64 rows x 192 ch, LayerNorm, write transposed ----
    {
        const int row = t >> 2, part = t & 3;             // 4 lanes per row
        const float* xp = xin + (size_t)(p0 + row) * CH + part * 48;
        float vals[48];
#pragma unroll
        for (int j = 0; j < 12; ++j) {
            float4 v4 = *(const float4*)(xp + j * 4);
            vals[j*4+0] = v4.x; vals[j*4+1] = v4.y; vals[j*4+2] = v4.z; vals[j*4+3] = v4.w;
        }
        if (do_ln) {
            float s = 0.f, s2 = 0.f;
#pragma unroll
            for (int j = 0; j < 48; ++j) { s += vals[j]; s2 += vals[j]*vals[j]; }
            s  += __shfl_xor(s, 1);  s2 += __shfl_xor(s2, 1);
            s  += __shfl_xor(s, 2);  s2 += __shfl_xor(s2, 2);
            const float mu = s * (1.f/192.f);
            const float rs = rsqrtf(s2 * (1.f/192.f) - mu*mu + 1e-5f);
#pragma unroll
            for (int j = 0; j < 48; ++j) {
                const int c = part*48 + j;
                vals[j] = (vals[j] - mu) * rs * lng[c] + lnb[c];
            }
        }
#pragma unroll
        for (int j = 0; j < 48; ++j) Atr[part*48 + j][row] = vals[j];
    }

    // ---- GEMM: thread (ty,tx) computes rows ty*4..+3, cols tx*12..+11 ----
    const int ty = t >> 4, tx = t & 15;
    float4 acc[4][3];
#pragma unroll
    for (int mm = 0; mm < 4; ++mm)
#pragma unroll
        for (int c = 0; c < 3; ++c) acc[mm][c] = make_float4(0.f,0.f,0.f,0.f);

    for (int k0 = 0; k0 < CH; k0 += 16) {
        __syncthreads();                 // Bs consumed (and Atr ready on iter 0)
#pragma unroll
        for (int i = 0; i < 3; ++i) {    // stage Bs[kk][n] = w[n][k0+kk]
            const int f = t + i * 256;
            const int n = f >> 2, c4 = f & 3;
            const float4 wv = *(const float4*)(wmat + n * CH + k0 + c4 * 4);
            Bs[c4*4+0][n] = wv.x; Bs[c4*4+1][n] = wv.y;
            Bs[c4*4+2][n] = wv.z; Bs[c4*4+3][n] = wv.w;
        }
        __syncthreads();
#pragma unroll
        for (int kk = 0; kk < 16; ++kk) {
            const float4 a4 = *(const float4*)&Atr[k0 + kk][ty * 4];
            const float4 b0 = *(const float4*)&Bs[kk][tx * 12];
            const float4 b1 = *(const float4*)&Bs[kk][tx * 12 + 4];
            const float4 b2 = *(const float4*)&Bs[kk][tx * 12 + 8];
            const float am[4] = {a4.x, a4.y, a4.z, a4.w};
#pragma unroll
            for (int mm = 0; mm < 4; ++mm) {
                fma4(acc[mm][0], am[mm], b0);
                fma4(acc[mm][1], am[mm], b1);
                fma4(acc[mm][2], am[mm], b2);
            }
        }
    }
#pragma unroll
    for (int mm = 0; mm < 4; ++mm) {
        float* yp = yout + (size_t)(p0 + ty*4 + mm) * CH + tx * 12;
        *(float4*)(yp)     = acc[mm][0];
        *(float4*)(yp + 4) = acc[mm][1];
        *(float4*)(yp + 8) = acc[mm][2];
    }
}

// ---------------------------------------------------------------------------
// K2: 3x3 depthwise conv (cross-correlation, SAME zero-pad) over NHWC fp32.
// One float4 (4 channels) per thread; weights transposed to [tap][c] in LDS.
// ---------------------------------------------------------------------------
__global__ __launch_bounds__(256) void dwconv_kernel(
    const float* __restrict__ in, const float* __restrict__ wdw, float* __restrict__ out)
{
    __shared__ float wt[9][CH];
    const int t = threadIdx.x;
    for (int idx = t; idx < CH * 9; idx += 256) {
        wt[idx % 9][idx / 9] = wdw[idx];   // wdw layout [c][ky][kx]
    }
    __syncthreads();
    const int gid = blockIdx.x * 256 + t;  // float4 index over (b,y,x,c4)
    const int c4 = gid % 48;
    int rest = gid / 48;
    const int x = rest % NWW; rest /= NWW;
    const int y = rest % NHH;
    const int b = rest / NHH;
    float4 acc = make_float4(0.f,0.f,0.f,0.f);
#pragma unroll
    for (int ky = 0; ky < 3; ++ky) {
        const int yy = y + ky - 1;
        if (yy < 0 || yy >= NHH) continue;
#pragma unroll
        for (int kx = 0; kx < 3; ++kx) {
            const int xx = x + kx - 1;
            if (xx < 0 || xx >= NWW) continue;
            const float4 iv = *(const float4*)(in + (size_t)((b*NHH + yy)*NWW + xx)*CH + c4*4);
            const float4 wv = *(const float4*)&wt[ky*3 + kx][c4*4];
            acc.x += iv.x*wv.x; acc.y += iv.y*wv.y; acc.z += iv.z*wv.z; acc.w += iv.w*wv.w;
        }
    }
    *(float4*)(out + (size_t)gid * 4) = acc;
}

// ---------------------------------------------------------------------------
// K3: per-(window, head) channel attention. Block = 256 threads (4 waves).
// LDS only qt/kt ([24][260] each, 49,920 B); v reuses qt after sim,
// partials/sim/attn reuse kt, output staging reuses qt.
//   sim[i][j] = sum_n q[i,n]k[j,n];  softmax_j;  out[i,n] = sum_j attn[i,j]v[j,n]
// ---------------------------------------------------------------------------
__global__ __launch_bounds__(256) void attn_kernel(
    const float* __restrict__ q, const float* __restrict__ k, const float* __restrict__ v,
    const float* __restrict__ rescale, float* __restrict__ out)
{
    __shared__ float qt[DH][260];
    __shared__ float kt[DH][260];
    float* pbuf = &kt[0][0];            // reused: partials[4*576] + sim/attn[576]
    const int t    = threadIdx.x;
    const int widx = blockIdx.x;        // b*256 + wy*16 + wx
    const int head = blockIdx.y;
    const int b  = widx >> 8;
    const int wy = (widx >> 4) & 15, wx = widx & 15;
    const int n  = t;                   // position within window
    const int gy = wy*WIN + (n >> 4), gx = wx*WIN + (n & 15);
    const size_t pbase = (size_t)((b*NHH + gy)*NWW + gx) * CH + head*DH;

    // phase A: load q,k transposed into LDS
#pragma unroll
    for (int j4 = 0; j4 < 6; ++j4) {
        const float4 qv = *(const float4*)(q + pbase + j4*4);
        qt[j4*4+0][n]=qv.x; qt[j4*4+1][n]=qv.y; qt[j4*4+2][n]=qv.z; qt[j4*4+3][n]=qv.w;
        const float4 kv = *(const float4*)(k + pbase + j4*4);
        kt[j4*4+0][n]=kv.x; kt[j4*4+1][n]=kv.y; kt[j4*4+2][n]=kv.z; kt[j4*4+3][n]=kv.w;
    }
    __syncthreads();

    // phase B: sim partials; each wave covers 64 of n, thread = 3x3 (i,j) block
    const int wvi  = t >> 6;
    const int lane = t & 63;
    const int i0 = (lane >> 3) * 3, j0 = (lane & 7) * 3;
    float s[3][3];
#pragma unroll
    for (int a = 0; a < 3; ++a)
#pragma unroll
        for (int c = 0; c < 3; ++c) s[a][c] = 0.f;
    for (int nn = wvi*64; nn < wvi*64 + 64; nn += 4) {
        float4 qv[3], kv[3];
#pragma unroll
        for (int a = 0; a < 3; ++a) {
            qv[a] = *(const float4*)&qt[i0+a][nn];
            kv[a] = *(const float4*)&kt[j0+a][nn];
        }
#pragma unroll
        for (int a = 0; a < 3; ++a)
#pragma unroll
            for (int c = 0; c < 3; ++c)
                s[a][c] += qv[a].x*kv[c].x + qv[a].y*kv[c].y + qv[a].z*kv[c].z + qv[a].w*kv[c].w;
    }
    __syncthreads();   // q,k fully consumed

    // phase C: partials -> kt-flat; v -> qt
#pragma unroll
    for (int a = 0; a < 3; ++a)
#pragma unroll
        for (int c = 0; c < 3; ++c)
            pbuf[wvi*576 + (i0+a)*24 + (j0+c)] = s[a][c];
#pragma unroll
    for (int j4 = 0; j4 < 6; ++j4) {
        const float4 vv = *(const float4*)(v + pbase + j4*4);
        qt[j4*4+0][n]=vv.x; qt[j4*4+1][n]=vv.y; qt[j4*4+2][n]=vv.z; qt[j4*4+3][n]=vv.w;
    }
    __syncthreads();

    // phase D: reduce 4 wave-partials + rescale
    const float rsc = rescale[head];
    for (int e = t; e < 576; e += 256) {
        const float sum = pbuf[e] + pbuf[576+e] + pbuf[1152+e] + pbuf[1728+e];
        pbuf[2304 + e] = sum * rsc;
    }
    __syncthreads();

    // phase E: softmax over j per row i
    if (t < 24) {
        float* srow = pbuf + 2304 + t*24;
        float m = srow[0];
#pragma unroll
        for (int j = 1; j < 24; ++j) m = fmaxf(m, srow[j]);
        float ssum = 0.f;
#pragma unroll
        for (int j = 0; j < 24; ++j) { const float e_ = expf(srow[j] - m); srow[j] = e_; ssum += e_; }
        const float inv = 1.f / ssum;
#pragma unroll
        for (int j = 0; j < 24; ++j) srow[j] *= inv;
    }
    __syncthreads();

    // phase F: PV — thread (iw,nc): 6 i-rows x one 4-wide n-chunk
    const int nc = t & 63;
    const int ib = (t >> 6) * 6;
    float4 acc[6];
#pragma unroll
    for (int ii = 0; ii < 6; ++ii) acc[ii] = make_float4(0.f,0.f,0.f,0.f);
#pragma unroll
    for (int j = 0; j < 24; ++j) {
        const float4 vj = *(const float4*)&qt[j][nc*4];
#pragma unroll
        for (int ii = 0; ii < 6; ++ii)
            fma4(acc[ii], pbuf[2304 + (ib+ii)*24 + j], vj);
    }
    __syncthreads();   // all PV reads of qt(v) done
    // phase G: stage output into qt for coalesced store
#pragma unroll
    for (int ii = 0; ii < 6; ++ii)
        *(float4*)&qt[ib+ii][nc*4] = acc[ii];
    __syncthreads();
    // phase H: coalesced store, lane n writes its 24 channels
#pragma unroll
    for (int c4 = 0; c4 < 6; ++c4) {
        float4 o;
        o.x = qt[c4*4+0][n]; o.y = qt[c4*4+1][n]; o.z = qt[c4*4+2][n]; o.w = qt[c4*4+3][n];
        *(float4*)(out + pbase + c4*4) = o;
    }
}

// ---------------------------------------------------------------------------
extern "C" void kernel_launch(void* const* d_in, const int* in_sizes, int n_in,
                              void* d_out, int out_size, void* d_ws, size_t ws_size,
                              hipStream_t stream)
{
    (void)in_sizes; (void)n_in; (void)out_size; (void)ws_size;
    const float* x     = (const float*)d_in[0];
    const float* ln_g  = (const float*)d_in[1];
    const float* ln_b  = (const float*)d_in[2];
    const float* wq1   = (const float*)d_in[3];
    const float* wq2   = (const float*)d_in[4];
    const float* wk1   = (const float*)d_in[5];
    const float* wk2   = (const float*)d_in[6];
    const float* wv1   = (const float*)d_in[7];
    const float* wv2   = (const float*)d_in[8];
    const float* rsc   = (const float*)d_in[9];
    const float* w_out = (const float*)d_in[10];
    float* out = (float*)d_out;

    const size_t NT = (size_t)NPOS * CH;       // 50,331,648 floats per tensor
    float* b1 = (float*)d_ws;                  // ws use: 4 * 201.3 MB = 805 MB
    float* b2 = b1 + NT;
    float* b3 = b2 + NT;
    float* b4 = b3 + NT;

    // LN + QKV pointwise GEMMs (z selects q/k/v)
    ln_gemm_kernel<<<dim3(NPOS/64, 1, 3), 256, 0, stream>>>(
        x, ln_g, ln_b, wq1, wk1, wv1, b1, b2, b3, 1);
    // depthwise 3x3 (buffer rotation: yq->b4, yk->b1, yv->b2)
    const int dwblocks = (int)(NT / 4 / 256);
    dwconv_kernel<<<dim3(dwblocks), 256, 0, stream>>>(b1, wq2, b4);
    dwconv_kernel<<<dim3(dwblocks), 256, 0, stream>>>(b2, wk2, b1);
    dwconv_kernel<<<dim3(dwblocks), 256, 0, stream>>>(b3, wv2, b2);
    // windowed channel attention: q=b4, k=b1, v=b2 -> b3
    attn_kernel<<<dim3(NB*16*16, HEADS), 256, 0, stream>>>(b4, b1, b2, rsc, b3);
    // output projection
    ln_gemm_kernel<<<dim3(NPOS/64, 1, 1), 256, 0, stream>>>(
        b3, ln_g, ln_b, w_out, w_out, w_out, out, out, out, 0);
}

// Round 2
// 844.488 us; speedup vs baseline: 2.7539x; 2.7539x over previous
//
#include <hip/hip_runtime.h>
#include <hip/hip_bf16.h>

#define CH    192
#define NB    4
#define NHH   256
#define NWW   256
#define NPOS  (NB*NHH*NWW)   // 262144
#define HEADS 8
#define DH    24
#define WIN   16

typedef unsigned short u16;
typedef __bf16 bf16x8 __attribute__((ext_vector_type(8)));
typedef float  f32x4  __attribute__((ext_vector_type(4)));
typedef u16    u16x8  __attribute__((ext_vector_type(8)));

__device__ __forceinline__ float b2f(u16 h) {
    union { unsigned int u; float f; } x; x.u = ((unsigned int)h) << 16; return x.f;
}
__device__ __forceinline__ u16 f2b(float f) {   // RNE
    union { float f; unsigned int u; } x; x.f = f;
    return (u16)((x.u + 0x7fffu + ((x.u >> 16) & 1u)) >> 16);
}

// ---------------------------------------------------------------------------
// P0: pack 4 weight matrices (fp32 [o][i]) into MFMA B-fragment order, bf16.
// pack[((mat*12 + ntile)*6 + kstep)*512 + lane*8 + j] =
//      w[mat][ntile*16 + (lane&15)][kstep*32 + (lane>>4)*8 + j]
// ---------------------------------------------------------------------------
__global__ __launch_bounds__(256) void prep_weights(
    const float* __restrict__ w0, const float* __restrict__ w1,
    const float* __restrict__ w2, const float* __restrict__ w3,
    u16* __restrict__ pack)
{
    const int t = blockIdx.x * 256 + threadIdx.x;   // 18432 total
    const int lane = t & 63, g = t >> 6;            // g: 0..287
    const int mat = g / 72;
    const float* w = (mat == 0) ? w0 : (mat == 1) ? w1 : (mat == 2) ? w2 : w3;
    const int nt = (g / 6) % 12, ks = g % 6;
    const float* src = w + (nt*16 + (lane & 15)) * CH + ks*32 + (lane >> 4) * 8;
    const float4 a = *(const float4*)(src);
    const float4 b = *(const float4*)(src + 4);
    u16x8 o;
    o[0]=f2b(a.x); o[1]=f2b(a.y); o[2]=f2b(a.z); o[3]=f2b(a.w);
    o[4]=f2b(b.x); o[5]=f2b(b.y); o[6]=f2b(b.z); o[7]=f2b(b.w);
    *(u16x8*)(pack + (size_t)g*512 + lane*8) = o;
}

// ---------------------------------------------------------------------------
// K0: LayerNorm fp32 -> bf16.  4 lanes per row (48 ch each), shfl-reduce.
// ---------------------------------------------------------------------------
__global__ __launch_bounds__(256) void ln_kernel(
    const float* __restrict__ x, const float* __restrict__ lng,
    const float* __restrict__ lnb, u16* __restrict__ xn)
{
    const int t = threadIdx.x;
    const int row = t >> 2, part = t & 3;
    const size_t p = (size_t)blockIdx.x * 64 + row;
    const float* xp = x + p * CH + part * 48;
    float vals[48];
#pragma unroll
    for (int j = 0; j < 12; ++j) {
        float4 v4 = *(const float4*)(xp + j * 4);
        vals[j*4+0]=v4.x; vals[j*4+1]=v4.y; vals[j*4+2]=v4.z; vals[j*4+3]=v4.w;
    }
    float s = 0.f, s2 = 0.f;
#pragma unroll
    for (int j = 0; j < 48; ++j) { s += vals[j]; s2 += vals[j]*vals[j]; }
    s += __shfl_xor(s, 1);  s2 += __shfl_xor(s2, 1);
    s += __shfl_xor(s, 2);  s2 += __shfl_xor(s2, 2);
    const float mu = s * (1.f/192.f);
    const float rs = rsqrtf(s2 * (1.f/192.f) - mu*mu + 1e-5f);
    u16 ov[48];
#pragma unroll
    for (int j = 0; j < 48; ++j) {
        const int c = part*48 + j;
        ov[j] = f2b((vals[j] - mu) * rs * lng[c] + lnb[c]);
    }
    u16* op = xn + p * CH + part * 48;
#pragma unroll
    for (int j8 = 0; j8 < 6; ++j8)
        *(u16x8*)(op + j8*8) = *(u16x8*)(ov + j8*8);
}

// ---------------------------------------------------------------------------
// K1: bf16 MFMA GEMM  y[p][n] = sum_k a[p][k] * w[n][k]   (K=N=192)
// Block: 256 thr = 2x2 waves over (M=128, N=192). Wave: 4 m-tiles x 6 n-tiles.
// A-frags direct from global bf16; B-frags from prepacked global (L2/L3-hot).
// blockIdx.y selects matrix (q/k/v); yf!=null -> fp32 output (out-proj).
// ---------------------------------------------------------------------------
__global__ __launch_bounds__(256) void gemm_mfma(
    const u16* __restrict__ a, const u16* __restrict__ bpack, int matoff,
    u16* __restrict__ y0, u16* __restrict__ y1, u16* __restrict__ y2,
    float* __restrict__ yf)
{
    const int t = threadIdx.x, l = t & 63, w = t >> 6;
    const int wm = w >> 1, wn = w & 1;
    const int lr = l & 15, lg = l >> 4;
    const size_t p0 = (size_t)blockIdx.x * 128;
    const int mat = blockIdx.y;
    const int mbase = wm * 64;            // 4 m-tiles
    const int nbase16 = wn * 6;           // 6 n-tiles
    const u16* bp = bpack + (size_t)(matoff + mat) * 36864 + (size_t)nbase16 * 6 * 512 + l * 8;
    const u16* ap = a + (p0 + mbase + lr) * CH + lg * 8;
    u16* yb = (mat == 0) ? y0 : (mat == 1) ? y1 : y2;

    f32x4 acc[4][6];
#pragma unroll
    for (int mt = 0; mt < 4; ++mt)
#pragma unroll
        for (int nt = 0; nt < 6; ++nt) acc[mt][nt] = (f32x4){0.f,0.f,0.f,0.f};

#pragma unroll
    for (int ks = 0; ks < 6; ++ks) {
        bf16x8 af[4], bfr[6];
#pragma unroll
        for (int mt = 0; mt < 4; ++mt)
            af[mt] = *(const bf16x8*)(ap + (size_t)mt*16*CH + ks*32);
#pragma unroll
        for (int nt = 0; nt < 6; ++nt)
            bfr[nt] = *(const bf16x8*)(bp + (size_t)(nt*6 + ks)*512);
#pragma unroll
        for (int mt = 0; mt < 4; ++mt)
#pragma unroll
            for (int nt = 0; nt < 6; ++nt)
                acc[mt][nt] = __builtin_amdgcn_mfma_f32_16x16x32_bf16(
                    af[mt], bfr[nt], acc[mt][nt], 0, 0, 0);
    }

#pragma unroll
    for (int mt = 0; mt < 4; ++mt) {
#pragma unroll
        for (int nt = 0; nt < 6; ++nt) {
            const int col = nbase16*16 + nt*16 + lr;
#pragma unroll
            for (int reg = 0; reg < 4; ++reg) {
                const size_t row = p0 + mbase + mt*16 + lg*4 + reg;
                if (yf) yf[row * CH + col] = acc[mt][nt][reg];
                else    yb[row * CH + col] = f2b(acc[mt][nt][reg]);
            }
        }
    }
}

// ---------------------------------------------------------------------------
// K2: 3x3 depthwise conv, bf16 in/out, fp32 accumulate, SAME zero-pad.
// ---------------------------------------------------------------------------
__global__ __launch_bounds__(256) void dwconv_kernel(
    const u16* __restrict__ in, const float* __restrict__ wdw, u16* __restrict__ out)
{
    __shared__ float wt[9][CH];
    const int t = threadIdx.x;
    for (int idx = t; idx < CH * 9; idx += 256)
        wt[idx % 9][idx / 9] = wdw[idx];    // wdw layout [c][ky][kx]
    __syncthreads();
    const int gid = blockIdx.x * 256 + t;   // u16x8 chunk over (b,y,x,c8)
    const int c8 = gid % 24;
    int rest = gid / 24;
    const int x = rest & 255; rest >>= 8;
    const int y = rest & 255;
    const int b = rest >> 8;
    float acc[8] = {0,0,0,0,0,0,0,0};
#pragma unroll
    for (int ky = 0; ky < 3; ++ky) {
        const int yy = y + ky - 1;
        if (yy < 0 || yy >= NHH) continue;
#pragma unroll
        for (int kx = 0; kx < 3; ++kx) {
            const int xx = x + kx - 1;
            if (xx < 0 || xx >= NWW) continue;
            const u16x8 iv = *(const u16x8*)(in + (size_t)((b*NHH + yy)*NWW + xx)*CH + c8*8);
            const float* wr = &wt[ky*3 + kx][c8*8];
#pragma unroll
            for (int j = 0; j < 8; ++j) acc[j] += b2f(iv[j]) * wr[j];
        }
    }
    u16x8 ov;
#pragma unroll
    for (int j = 0; j < 8; ++j) ov[j] = f2b(acc[j]);
    *(u16x8*)(out + (size_t)gid * 8) = ov;
}

// ---------------------------------------------------------------------------
// K3: per-(window, head) channel attention, bf16 I/O, fp32 LDS/compute.
// ---------------------------------------------------------------------------
__global__ __launch_bounds__(256) void attn_kernel(
    const u16* __restrict__ q, const u16* __restrict__ k, const u16* __restrict__ v,
    const float* __restrict__ rescale, u16* __restrict__ out)
{
    __shared__ float qt[DH][260];
    __shared__ float kt[DH][260];
    float* pbuf = &kt[0][0];            // reused: partials[4*576] + sim/attn[576]
    const int t    = threadIdx.x;
    const int widx = blockIdx.x;        // b*256 + wy*16 + wx
    const int head = blockIdx.y;
    const int b  = widx >> 8;
    const int wy = (widx >> 4) & 15, wx = widx & 15;
    const int n  = t;
    const int gy = wy*WIN + (n >> 4), gx = wx*WIN + (n & 15);
    const size_t pbase = (size_t)((b*NHH + gy)*NWW + gx) * CH + head*DH;

    // phase A: q,k transposed into LDS (fp32)
#pragma unroll
    for (int j8 = 0; j8 < 3; ++j8) {
        const u16x8 qv = *(const u16x8*)(q + pbase + j8*8);
        const u16x8 kv = *(const u16x8*)(k + pbase + j8*8);
#pragma unroll
        for (int j = 0; j < 8; ++j) { qt[j8*8+j][n] = b2f(qv[j]); kt[j8*8+j][n] = b2f(kv[j]); }
    }
    __syncthreads();

    // phase B: sim partials; wave covers 64 of n, thread = 3x3 (i,j) block
    const int wvi  = t >> 6;
    const int lane = t & 63;
    const int i0 = (lane >> 3) * 3, j0 = (lane & 7) * 3;
    float s[3][3];
#pragma unroll
    for (int a2 = 0; a2 < 3; ++a2)
#pragma unroll
        for (int c = 0; c < 3; ++c) s[a2][c] = 0.f;
    for (int nn = wvi*64; nn < wvi*64 + 64; nn += 4) {
        float4 qv[3], kv[3];
#pragma unroll
        for (int a2 = 0; a2 < 3; ++a2) {
            qv[a2] = *(const float4*)&qt[i0+a2][nn];
            kv[a2] = *(const float4*)&kt[j0+a2][nn];
        }
#pragma unroll
        for (int a2 = 0; a2 < 3; ++a2)
#pragma unroll
            for (int c = 0; c < 3; ++c)
                s[a2][c] += qv[a2].x*kv[c].x + qv[a2].y*kv[c].y + qv[a2].z*kv[c].z + qv[a2].w*kv[c].w;
    }
    __syncthreads();

    // phase C: partials -> kt-flat; v -> qt
#pragma unroll
    for (int a2 = 0; a2 < 3; ++a2)
#pragma unroll
        for (int c = 0; c < 3; ++c)
            pbuf[wvi*576 + (i0+a2)*24 + (j0+c)] = s[a2][c];
#pragma unroll
    for (int j8 = 0; j8 < 3; ++j8) {
        const u16x8 vv = *(const u16x8*)(v + pbase + j8*8);
#pragma unroll
        for (int j = 0; j < 8; ++j) qt[j8*8+j][n] = b2f(vv[j]);
    }
    __syncthreads();

    // phase D: reduce 4 wave-partials + rescale
    const float rsc = rescale[head];
    for (int e = t; e < 576; e += 256) {
        const float sum = pbuf[e] + pbuf[576+e] + pbuf[1152+e] + pbuf[1728+e];
        pbuf[2304 + e] = sum * rsc;
    }
    __syncthreads();

    // phase E: softmax over j per row i
    if (t < 24) {
        float* srow = pbuf + 2304 + t*24;
        float m = srow[0];
#pragma unroll
        for (int j = 1; j < 24; ++j) m = fmaxf(m, srow[j]);
        float ssum = 0.f;
#pragma unroll
        for (int j = 0; j < 24; ++j) { const float e_ = expf(srow[j] - m); srow[j] = e_; ssum += e_; }
        const float inv = 1.f / ssum;
#pragma unroll
        for (int j = 0; j < 24; ++j) srow[j] *= inv;
    }
    __syncthreads();

    // phase F: PV — thread (iw,nc): 6 i-rows x one 4-wide n-chunk
    const int nc = t & 63;
    const int ib = (t >> 6) * 6;
    float4 acc[6];
#pragma unroll
    for (int ii = 0; ii < 6; ++ii) acc[ii] = make_float4(0.f,0.f,0.f,0.f);
#pragma unroll
    for (int j = 0; j < 24; ++j) {
        const float4 vj = *(const float4*)&qt[j][nc*4];
        const float aw0 = pbuf[2304 + (ib+0)*24 + j];
        const float aw1 = pbuf[2304 + (ib+1)*24 + j];
        const float aw2 = pbuf[2304 + (ib+2)*24 + j];
        const float aw3 = pbuf[2304 + (ib+3)*24 + j];
        const float aw4 = pbuf[2304 + (ib+4)*24 + j];
        const float aw5 = pbuf[2304 + (ib+5)*24 + j];
        acc[0].x += aw0*vj.x; acc[0].y += aw0*vj.y; acc[0].z += aw0*vj.z; acc[0].w += aw0*vj.w;
        acc[1].x += aw1*vj.x; acc[1].y += aw1*vj.y; acc[1].z += aw1*vj.z; acc[1].w += aw1*vj.w;
        acc[2].x += aw2*vj.x; acc[2].y += aw2*vj.y; acc[2].z += aw2*vj.z; acc[2].w += aw2*vj.w;
        acc[3].x += aw3*vj.x; acc[3].y += aw3*vj.y; acc[3].z += aw3*vj.z; acc[3].w += aw3*vj.w;
        acc[4].x += aw4*vj.x; acc[4].y += aw4*vj.y; acc[4].z += aw4*vj.z; acc[4].w += aw4*vj.w;
        acc[5].x += aw5*vj.x; acc[5].y += aw5*vj.y; acc[5].z += aw5*vj.z; acc[5].w += aw5*vj.w;
    }
    __syncthreads();
    // phase G: stage output fp32 into qt
#pragma unroll
    for (int ii = 0; ii < 6; ++ii)
        *(float4*)&qt[ib+ii][nc*4] = acc[ii];
    __syncthreads();
    // phase H: coalesced bf16 store, lane n writes its 24 channels
#pragma unroll
    for (int j8 = 0; j8 < 3; ++j8) {
        u16x8 o;
#pragma unroll
        for (int j = 0; j < 8; ++j) o[j] = f2b(qt[j8*8+j][n]);
        *(u16x8*)(out + pbase + j8*8) = o;
    }
}

// ---------------------------------------------------------------------------
extern "C" void kernel_launch(void* const* d_in, const int* in_sizes, int n_in,
                              void* d_out, int out_size, void* d_ws, size_t ws_size,
                              hipStream_t stream)
{
    (void)in_sizes; (void)n_in; (void)out_size; (void)ws_size;
    const float* x     = (const float*)d_in[0];
    const float* ln_g  = (const float*)d_in[1];
    const float* ln_b  = (const float*)d_in[2];
    const float* wq1   = (const float*)d_in[3];
    const float* wq2   = (const float*)d_in[4];
    const float* wk1   = (const float*)d_in[5];
    const float* wk2   = (const float*)d_in[6];
    const float* wv1   = (const float*)d_in[7];
    const float* wv2   = (const float*)d_in[8];
    const float* rsc   = (const float*)d_in[9];
    const float* w_out = (const float*)d_in[10];
    float* out = (float*)d_out;

    const size_t NT = (size_t)NPOS * CH;    // 50,331,648 elems
    u16* u0 = (u16*)d_ws;                   // xn (bf16)
    u16* u1 = u0 + NT;
    u16* u2 = u1 + NT;
    u16* u3 = u2 + NT;
    u16* u4 = u3 + NT;
    u16* pack = u4 + NT;                    // 147,456 u16

    prep_weights<<<72, 256, 0, stream>>>(wq1, wk1, wv1, w_out, pack);
    ln_kernel<<<NPOS/64, 256, 0, stream>>>(x, ln_g, ln_b, u0);
    // QKV pointwise GEMMs (blockIdx.y = q/k/v)
    gemm_mfma<<<dim3(NPOS/128, 3), 256, 0, stream>>>(u0, pack, 0, u1, u2, u3, nullptr);
    // depthwise 3x3:  q:u1->u4   k:u2->u1   v:u3->u2
    const int dwblocks = (int)(NT / 8 / 256);
    dwconv_kernel<<<dwblocks, 256, 0, stream>>>(u1, wq2, u4);
    dwconv_kernel<<<dwblocks, 256, 0, stream>>>(u2, wk2, u1);
    dwconv_kernel<<<dwblocks, 256, 0, stream>>>(u3, wv2, u2);
    // windowed channel attention: q=u4, k=u1, v=u2 -> u3
    attn_kernel<<<dim3(NB*256, HEADS), 256, 0, stream>>>(u4, u1, u2, rsc, u3);
    // output projection (fp32 out)
    gemm_mfma<<<dim3(NPOS/128, 1), 256, 0, stream>>>(u3, pack, 3, nullptr, nullptr, nullptr, out);
}

// Round 3
// 714.925 us; speedup vs baseline: 3.2529x; 1.1812x over previous
//
#include <hip/hip_runtime.h>
#include <hip/hip_bf16.h>

#define CH    192
#define NB    4
#define NHH   256
#define NWW   256
#define NPOS  (NB*NHH*NWW)   // 262144
#define HEADS 8
#define DH    24
#define WIN   16
#define PS    ((size_t)NPOS*DH)   // head-plane stride (elems)

typedef unsigned short u16;
typedef __bf16 bf16x8 __attribute__((ext_vector_type(8)));
typedef float  f32x4  __attribute__((ext_vector_type(4)));
typedef u16    u16x8  __attribute__((ext_vector_type(8)));

__device__ __forceinline__ float b2f(u16 h) {
    union { unsigned int u; float f; } x; x.u = ((unsigned int)h) << 16; return x.f;
}
__device__ __forceinline__ u16 f2b(float f) {   // RNE
    union { float f; unsigned int u; } x; x.f = f;
    return (u16)((x.u + 0x7fffu + ((x.u >> 16) & 1u)) >> 16);
}

// ---------------------------------------------------------------------------
// P0: pack 4 weight matrices (fp32 [o][i]) into MFMA B-fragment order, bf16.
// ---------------------------------------------------------------------------
__global__ __launch_bounds__(256) void prep_weights(
    const float* __restrict__ w0, const float* __restrict__ w1,
    const float* __restrict__ w2, const float* __restrict__ w3,
    u16* __restrict__ pack)
{
    const int t = blockIdx.x * 256 + threadIdx.x;   // 18432 total
    const int lane = t & 63, g = t >> 6;            // g: 0..287
    const int mat = g / 72;
    const float* w = (mat == 0) ? w0 : (mat == 1) ? w1 : (mat == 2) ? w2 : w3;
    const int nt = (g / 6) % 12, ks = g % 6;
    const float* src = w + (nt*16 + (lane & 15)) * CH + ks*32 + (lane >> 4) * 8;
    const float4 a = *(const float4*)(src);
    const float4 b = *(const float4*)(src + 4);
    u16x8 o;
    o[0]=f2b(a.x); o[1]=f2b(a.y); o[2]=f2b(a.z); o[3]=f2b(a.w);
    o[4]=f2b(b.x); o[5]=f2b(b.y); o[6]=f2b(b.z); o[7]=f2b(b.w);
    *(u16x8*)(pack + (size_t)g*512 + lane*8) = o;
}

// ---------------------------------------------------------------------------
// K0: LayerNorm fp32 -> bf16 (NHWC).  4 lanes per row, shfl-reduce.
// ---------------------------------------------------------------------------
__global__ __launch_bounds__(256) void ln_kernel(
    const float* __restrict__ x, const float* __restrict__ lng,
    const float* __restrict__ lnb, u16* __restrict__ xn)
{
    const int t = threadIdx.x;
    const int row = t >> 2, part = t & 3;
    const size_t p = (size_t)blockIdx.x * 64 + row;
    const float* xp = x + p * CH + part * 48;
    float vals[48];
#pragma unroll
    for (int j = 0; j < 12; ++j) {
        float4 v4 = *(const float4*)(xp + j * 4);
        vals[j*4+0]=v4.x; vals[j*4+1]=v4.y; vals[j*4+2]=v4.z; vals[j*4+3]=v4.w;
    }
    float s = 0.f, s2 = 0.f;
#pragma unroll
    for (int j = 0; j < 48; ++j) { s += vals[j]; s2 += vals[j]*vals[j]; }
    s += __shfl_xor(s, 1);  s2 += __shfl_xor(s2, 1);
    s += __shfl_xor(s, 2);  s2 += __shfl_xor(s2, 2);
    const float mu = s * (1.f/192.f);
    const float rs = rsqrtf(s2 * (1.f/192.f) - mu*mu + 1e-5f);
    u16 ov[48];
#pragma unroll
    for (int j = 0; j < 48; ++j) {
        const int c = part*48 + j;
        ov[j] = f2b((vals[j] - mu) * rs * lng[c] + lnb[c]);
    }
    u16* op = xn + p * CH + part * 48;
#pragma unroll
    for (int j8 = 0; j8 < 6; ++j8)
        *(u16x8*)(op + j8*8) = *(u16x8*)(ov + j8*8);
}

// ---------------------------------------------------------------------------
// K1: bf16 MFMA GEMM  y[p][n] = sum_k a[p][k] * w[n][k]   (K=N=192)
// a_headsep: A tensor stored [h][p][24] (out-proj reading attn output).
// bf16 outputs (y0/y1/y2) stored head-separated [h][p][24];
// yf != null -> final fp32 NHWC output.
// ---------------------------------------------------------------------------
__global__ __launch_bounds__(256) void gemm_mfma(
    const u16* __restrict__ a, const u16* __restrict__ bpack, int matoff, int a_headsep,
    u16* __restrict__ y0, u16* __restrict__ y1, u16* __restrict__ y2,
    float* __restrict__ yf)
{
    const int t = threadIdx.x, l = t & 63, w = t >> 6;
    const int wm = w >> 1, wn = w & 1;
    const int lr = l & 15, lg = l >> 4;
    const size_t p0 = (size_t)blockIdx.x * 128;
    const int mat = blockIdx.y;
    const int mbase = wm * 64;            // 4 m-tiles
    const int nbase16 = wn * 6;           // 6 n-tiles
    const u16* bp = bpack + (size_t)(matoff + mat) * 36864 + (size_t)nbase16 * 6 * 512 + l * 8;
    const size_t prow = p0 + mbase + lr;
    u16* yb = (mat == 0) ? y0 : (mat == 1) ? y1 : y2;

    f32x4 acc[4][6];
#pragma unroll
    for (int mt = 0; mt < 4; ++mt)
#pragma unroll
        for (int nt = 0; nt < 6; ++nt) acc[mt][nt] = (f32x4){0.f,0.f,0.f,0.f};

#pragma unroll
    for (int ks = 0; ks < 6; ++ks) {
        bf16x8 af[4], bfr[6];
        if (a_headsep) {
            const int ch0 = ks*32 + lg*8;
            const int hh = ch0 / 24, cc = ch0 - hh*24;
            const u16* ap = a + (size_t)hh*PS + prow*DH + cc;
#pragma unroll
            for (int mt = 0; mt < 4; ++mt)
                af[mt] = *(const bf16x8*)(ap + (size_t)mt*16*DH);
        } else {
            const u16* ap = a + prow*CH + lg*8 + ks*32;
#pragma unroll
            for (int mt = 0; mt < 4; ++mt)
                af[mt] = *(const bf16x8*)(ap + (size_t)mt*16*CH);
        }
#pragma unroll
        for (int nt = 0; nt < 6; ++nt)
            bfr[nt] = *(const bf16x8*)(bp + (size_t)(nt*6 + ks)*512);
#pragma unroll
        for (int mt = 0; mt < 4; ++mt)
#pragma unroll
            for (int nt = 0; nt < 6; ++nt)
                acc[mt][nt] = __builtin_amdgcn_mfma_f32_16x16x32_bf16(
                    af[mt], bfr[nt], acc[mt][nt], 0, 0, 0);
    }

#pragma unroll
    for (int mt = 0; mt < 4; ++mt) {
#pragma unroll
        for (int nt = 0; nt < 6; ++nt) {
            const int col = nbase16*16 + nt*16 + lr;
            const int hh = col / 24, cc = col - hh*24;
#pragma unroll
            for (int reg = 0; reg < 4; ++reg) {
                const size_t row = p0 + mbase + mt*16 + lg*4 + reg;
                if (yf) yf[row * CH + col] = acc[mt][nt][reg];
                else    yb[(size_t)hh*PS + row*DH + cc] = f2b(acc[mt][nt][reg]);
            }
        }
    }
}

// ---------------------------------------------------------------------------
// K2: 3x3 depthwise conv per head-plane [h][b][y][x][24], bf16, fp32 accum.
// blockIdx.y = head. Consecutive threads -> contiguous 16B chunks.
// ---------------------------------------------------------------------------
__global__ __launch_bounds__(256) void dwconv_kernel(
    const u16* __restrict__ in, const float* __restrict__ wdw, u16* __restrict__ out)
{
    __shared__ float wloc[DH*9];          // this head's weights [c][tap]
    const int t = threadIdx.x;
    const int h = blockIdx.y;
    if (t < DH*9) wloc[t] = wdw[h*DH*9 + t];
    __syncthreads();
    const int gid2 = blockIdx.x * 256 + t;   // in [0, NPOS*3)
    const int p  = gid2 / 3, c8 = gid2 - p*3;
    const int x = p & 255, y = (p >> 8) & 255, b = p >> 16;
    const size_t plane = (size_t)h * PS;
    float acc[8] = {0,0,0,0,0,0,0,0};
#pragma unroll
    for (int ky = 0; ky < 3; ++ky) {
        const int yy = y + ky - 1;
        if (yy < 0 || yy >= NHH) continue;
#pragma unroll
        for (int kx = 0; kx < 3; ++kx) {
            const int xx = x + kx - 1;
            if (xx < 0 || xx >= NWW) continue;
            const u16x8 iv = *(const u16x8*)(in + plane + (size_t)((b*NHH + yy)*NWW + xx)*DH + c8*8);
#pragma unroll
            for (int j = 0; j < 8; ++j)
                acc[j] += b2f(iv[j]) * wloc[(c8*8 + j)*9 + ky*3 + kx];
        }
    }
    u16x8 ov;
#pragma unroll
    for (int j = 0; j < 8; ++j) ov[j] = f2b(acc[j]);
    *(u16x8*)(out + plane + (size_t)p*DH + c8*8) = ov;
}

// ---------------------------------------------------------------------------
// K3: per-(window, head) channel attention; head-separated I/O.
// ---------------------------------------------------------------------------
__global__ __launch_bounds__(256) void attn_kernel(
    const u16* __restrict__ q, const u16* __restrict__ k, const u16* __restrict__ v,
    const float* __restrict__ rescale, u16* __restrict__ out)
{
    __shared__ float qt[DH][260];
    __shared__ float kt[DH][260];
    float* pbuf = &kt[0][0];            // reused: partials[4*576] + sim/attn[576]
    const int t    = threadIdx.x;
    const int widx = blockIdx.x;        // b*256 + wy*16 + wx
    const int h    = blockIdx.y;
    const int b  = widx >> 8;
    const int wy = (widx >> 4) & 15, wx = widx & 15;
    const int n  = t;
    const int gy = wy*WIN + (n >> 4), gx = wx*WIN + (n & 15);
    const size_t pbase = (size_t)h*PS + (size_t)((b*NHH + gy)*NWW + gx) * DH;

    // phase A: q,k transposed into LDS (fp32); contiguous 768B per window-row
#pragma unroll
    for (int j8 = 0; j8 < 3; ++j8) {
        const u16x8 qv = *(const u16x8*)(q + pbase + j8*8);
        const u16x8 kv = *(const u16x8*)(k + pbase + j8*8);
#pragma unroll
        for (int j = 0; j < 8; ++j) { qt[j8*8+j][n] = b2f(qv[j]); kt[j8*8+j][n] = b2f(kv[j]); }
    }
    __syncthreads();

    // phase B: sim partials; wave covers 64 of n, thread = 3x3 (i,j) block
    const int wvi  = t >> 6;
    const int lane = t & 63;
    const int i0 = (lane >> 3) * 3, j0 = (lane & 7) * 3;
    float s[3][3];
#pragma unroll
    for (int a2 = 0; a2 < 3; ++a2)
#pragma unroll
        for (int c = 0; c < 3; ++c) s[a2][c] = 0.f;
    for (int nn = wvi*64; nn < wvi*64 + 64; nn += 4) {
        float4 qv[3], kv[3];
#pragma unroll
        for (int a2 = 0; a2 < 3; ++a2) {
            qv[a2] = *(const float4*)&qt[i0+a2][nn];
            kv[a2] = *(const float4*)&kt[j0+a2][nn];
        }
#pragma unroll
        for (int a2 = 0; a2 < 3; ++a2)
#pragma unroll
            for (int c = 0; c < 3; ++c)
                s[a2][c] += qv[a2].x*kv[c].x + qv[a2].y*kv[c].y + qv[a2].z*kv[c].z + qv[a2].w*kv[c].w;
    }
    __syncthreads();

    // phase C: partials -> kt-flat; v -> qt
#pragma unroll
    for (int a2 = 0; a2 < 3; ++a2)
#pragma unroll
        for (int c = 0; c < 3; ++c)
            pbuf[wvi*576 + (i0+a2)*24 + (j0+c)] = s[a2][c];
#pragma unroll
    for (int j8 = 0; j8 < 3; ++j8) {
        const u16x8 vv = *(const u16x8*)(v + pbase + j8*8);
#pragma unroll
        for (int j = 0; j < 8; ++j) qt[j8*8+j][n] = b2f(vv[j]);
    }
    __syncthreads();

    // phase D: reduce 4 wave-partials + rescale
    const float rsc = rescale[h];
    for (int e = t; e < 576; e += 256) {
        const float sum = pbuf[e] + pbuf[576+e] + pbuf[1152+e] + pbuf[1728+e];
        pbuf[2304 + e] = sum * rsc;
    }
    __syncthreads();

    // phase E: softmax over j per row i
    if (t < 24) {
        float* srow = pbuf + 2304 + t*24;
        float m = srow[0];
#pragma unroll
        for (int j = 1; j < 24; ++j) m = fmaxf(m, srow[j]);
        float ssum = 0.f;
#pragma unroll
        for (int j = 0; j < 24; ++j) { const float e_ = expf(srow[j] - m); srow[j] = e_; ssum += e_; }
        const float inv = 1.f / ssum;
#pragma unroll
        for (int j = 0; j < 24; ++j) srow[j] *= inv;
    }
    __syncthreads();

    // phase F: PV — thread (iw,nc): 6 i-rows x one 4-wide n-chunk
    const int nc = t & 63;
    const int ib = (t >> 6) * 6;
    float4 acc[6];
#pragma unroll
    for (int ii = 0; ii < 6; ++ii) acc[ii] = make_float4(0.f,0.f,0.f,0.f);
#pragma unroll
    for (int j = 0; j < 24; ++j) {
        const float4 vj = *(const float4*)&qt[j][nc*4];
        const float aw0 = pbuf[2304 + (ib+0)*24 + j];
        const float aw1 = pbuf[2304 + (ib+1)*24 + j];
        const float aw2 = pbuf[2304 + (ib+2)*24 + j];
        const float aw3 = pbuf[2304 + (ib+3)*24 + j];
        const float aw4 = pbuf[2304 + (ib+4)*24 + j];
        const float aw5 = pbuf[2304 + (ib+5)*24 + j];
        acc[0].x += aw0*vj.x; acc[0].y += aw0*vj.y; acc[0].z += aw0*vj.z; acc[0].w += aw0*vj.w;
        acc[1].x += aw1*vj.x; acc[1].y += aw1*vj.y; acc[1].z += aw1*vj.z; acc[1].w += aw1*vj.w;
        acc[2].x += aw2*vj.x; acc[2].y += aw2*vj.y; acc[2].z += aw2*vj.z; acc[2].w += aw2*vj.w;
        acc[3].x += aw3*vj.x; acc[3].y += aw3*vj.y; acc[3].z += aw3*vj.z; acc[3].w += aw3*vj.w;
        acc[4].x += aw4*vj.x; acc[4].y += aw4*vj.y; acc[4].z += aw4*vj.z; acc[4].w += aw4*vj.w;
        acc[5].x += aw5*vj.x; acc[5].y += aw5*vj.y; acc[5].z += aw5*vj.z; acc[5].w += aw5*vj.w;
    }
    __syncthreads();
    // phase G: stage output fp32 into qt
#pragma unroll
    for (int ii = 0; ii < 6; ++ii)
        *(float4*)&qt[ib+ii][nc*4] = acc[ii];
    __syncthreads();
    // phase H: coalesced bf16 store (3KB contiguous per 64-lane wave)
#pragma unroll
    for (int j8 = 0; j8 < 3; ++j8) {
        u16x8 o;
#pragma unroll
        for (int j = 0; j < 8; ++j) o[j] = f2b(qt[j8*8+j][n]);
        *(u16x8*)(out + pbase + j8*8) = o;
    }
}

// ---------------------------------------------------------------------------
extern "C" void kernel_launch(void* const* d_in, const int* in_sizes, int n_in,
                              void* d_out, int out_size, void* d_ws, size_t ws_size,
                              hipStream_t stream)
{
    (void)in_sizes; (void)n_in; (void)out_size; (void)ws_size;
    const float* x     = (const float*)d_in[0];
    const float* ln_g  = (const float*)d_in[1];
    const float* ln_b  = (const float*)d_in[2];
    const float* wq1   = (const float*)d_in[3];
    const float* wq2   = (const float*)d_in[4];
    const float* wk1   = (const float*)d_in[5];
    const float* wk2   = (const float*)d_in[6];
    const float* wv1   = (const float*)d_in[7];
    const float* wv2   = (const float*)d_in[8];
    const float* rsc   = (const float*)d_in[9];
    const float* w_out = (const float*)d_in[10];
    float* out = (float*)d_out;

    const size_t NT = (size_t)NPOS * CH;    // 50,331,648 elems
    u16* u0 = (u16*)d_ws;                   // xn (bf16, NHWC)
    u16* u1 = u0 + NT;                      // head-sep tensors
    u16* u2 = u1 + NT;
    u16* u3 = u2 + NT;
    u16* u4 = u3 + NT;
    u16* pack = u4 + NT;                    // 147,456 u16

    prep_weights<<<72, 256, 0, stream>>>(wq1, wk1, wv1, w_out, pack);
    ln_kernel<<<NPOS/64, 256, 0, stream>>>(x, ln_g, ln_b, u0);
    // QKV pointwise GEMMs (blockIdx.y = q/k/v), outputs head-separated
    gemm_mfma<<<dim3(NPOS/128, 3), 256, 0, stream>>>(u0, pack, 0, 0, u1, u2, u3, nullptr);
    // depthwise 3x3 per head-plane:  q:u1->u4   k:u2->u1   v:u3->u2
    dwconv_kernel<<<dim3(NPOS*3/256, HEADS), 256, 0, stream>>>(u1, wq2, u4);
    dwconv_kernel<<<dim3(NPOS*3/256, HEADS), 256, 0, stream>>>(u2, wk2, u1);
    dwconv_kernel<<<dim3(NPOS*3/256, HEADS), 256, 0, stream>>>(u3, wv2, u2);
    // windowed channel attention: q=u4, k=u1, v=u2 -> u3 (head-sep)
    attn_kernel<<<dim3(NB*256, HEADS), 256, 0, stream>>>(u4, u1, u2, rsc, u3);
    // output projection (A head-sep, fp32 NHWC out)
    gemm_mfma<<<dim3(NPOS/128, 1), 256, 0, stream>>>(u3, pack, 3, 1, nullptr, nullptr, nullptr, out);
}

// Round 4
// 641.473 us; speedup vs baseline: 3.6254x; 1.1145x over previous
//
#include <hip/hip_runtime.h>
#include <hip/hip_bf16.h>

#define CH    192
#define NB    4
#define NHH   256
#define NWW   256
#define NPOS  (NB*NHH*NWW)   // 262144
#define HEADS 8
#define DH    24
#define WIN   16
#define PS    ((size_t)NPOS*DH)   // head-plane stride (elems)

typedef unsigned short u16;
typedef __bf16 bf16x8 __attribute__((ext_vector_type(8)));
typedef float  f32x4  __attribute__((ext_vector_type(4)));
typedef u16    u16x8  __attribute__((ext_vector_type(8)));

__device__ __forceinline__ float b2f(u16 h) {
    union { unsigned int u; float f; } x; x.u = ((unsigned int)h) << 16; return x.f;
}
__device__ __forceinline__ u16 f2b(float f) {   // RNE
    union { float f; unsigned int u; } x; x.f = f;
    return (u16)((x.u + 0x7fffu + ((x.u >> 16) & 1u)) >> 16);
}

// ---------------------------------------------------------------------------
// P0: pack 4 weight matrices (fp32 [o][i]) into MFMA B-fragment order, bf16.
// pack[((mat*12 + ntile)*6 + ks)*512 + lane*8 + j] =
//      w[mat][ntile*16 + (lane&15)][ks*32 + (lane>>4)*8 + j]
// ---------------------------------------------------------------------------
__global__ __launch_bounds__(256) void prep_weights(
    const float* __restrict__ w0, const float* __restrict__ w1,
    const float* __restrict__ w2, const float* __restrict__ w3,
    u16* __restrict__ pack)
{
    const int t = blockIdx.x * 256 + threadIdx.x;   // 18432 total
    const int lane = t & 63, g = t >> 6;            // g: 0..287
    const int mat = g / 72;
    const float* w = (mat == 0) ? w0 : (mat == 1) ? w1 : (mat == 2) ? w2 : w3;
    const int nt = (g / 6) % 12, ks = g % 6;
    const float* src = w + (nt*16 + (lane & 15)) * CH + ks*32 + (lane >> 4) * 8;
    const float4 a = *(const float4*)(src);
    const float4 b = *(const float4*)(src + 4);
    u16x8 o;
    o[0]=f2b(a.x); o[1]=f2b(a.y); o[2]=f2b(a.z); o[3]=f2b(a.w);
    o[4]=f2b(b.x); o[5]=f2b(b.y); o[6]=f2b(b.z); o[7]=f2b(b.w);
    *(u16x8*)(pack + (size_t)g*512 + lane*8) = o;
}

// ---------------------------------------------------------------------------
// K1: fused LayerNorm + QKV MFMA GEMM.
// Block: 64 rows x 192 cols, 256 thr (4 waves). Wave w covers n = w*48..+47.
// LN in-kernel -> bf16 A-tile in LDS [64][200] (400B row stride: 16B-aligned,
// bank-step 4 -> 2-way, free). Loop over q/k/v weight mats reusing the A-tile.
// Output staged via LDS -> contiguous 48B-per-(h,row) head-separated stores.
// Per-wave acc = 4x3 frags = 48 regs -> ~3-4 waves/SIMD (vs 2 in R3).
// ---------------------------------------------------------------------------
__global__ __launch_bounds__(256) void ln_qkv_gemm(
    const float* __restrict__ x, const float* __restrict__ lng, const float* __restrict__ lnb,
    const u16* __restrict__ bpack,
    u16* __restrict__ y0, u16* __restrict__ y1, u16* __restrict__ y2)
{
    __shared__ __align__(16) u16 At[64][200];   // 25,600 B
    __shared__ __align__(16) u16 St[64][200];   // 25,600 B  (total 51,200 -> 3 blk/CU)
    const int t = threadIdx.x, l = t & 63, w = t >> 6;
    const int lr = l & 15, lg = l >> 4;
    const size_t p0 = (size_t)blockIdx.x * 64;

    // ---- LN phase: 4 lanes per row (48 ch each), shfl-reduce, bf16 -> At ----
    {
        const int row = t >> 2, part = t & 3;
        const float* xp = x + (p0 + row) * CH + part * 48;
        float vals[48];
#pragma unroll
        for (int j = 0; j < 12; ++j) {
            float4 v4 = *(const float4*)(xp + j * 4);
            vals[j*4+0]=v4.x; vals[j*4+1]=v4.y; vals[j*4+2]=v4.z; vals[j*4+3]=v4.w;
        }
        float s = 0.f, s2 = 0.f;
#pragma unroll
        for (int j = 0; j < 48; ++j) { s += vals[j]; s2 += vals[j]*vals[j]; }
        s += __shfl_xor(s, 1);  s2 += __shfl_xor(s2, 1);
        s += __shfl_xor(s, 2);  s2 += __shfl_xor(s2, 2);
        const float mu = s * (1.f/192.f);
        const float rs = rsqrtf(s2 * (1.f/192.f) - mu*mu + 1e-5f);
#pragma unroll
        for (int j8 = 0; j8 < 6; ++j8) {
            u16x8 o;
#pragma unroll
            for (int j = 0; j < 8; ++j) {
                const int c = part*48 + j8*8 + j;
                o[j] = f2b((vals[j8*8+j] - mu) * rs * lng[c] + lnb[c]);
            }
            *(u16x8*)&At[row][part*48 + j8*8] = o;
        }
    }
    __syncthreads();

    // ---- GEMM over 3 weight matrices ----
    for (int mat = 0; mat < 3; ++mat) {
        u16* yb = (mat == 0) ? y0 : (mat == 1) ? y1 : y2;
        f32x4 acc[4][3];
#pragma unroll
        for (int mt = 0; mt < 4; ++mt)
#pragma unroll
            for (int nt = 0; nt < 3; ++nt) acc[mt][nt] = (f32x4){0.f,0.f,0.f,0.f};
        const u16* bp = bpack + (size_t)mat*36864 + (size_t)w*3*3072 + l*8;
#pragma unroll
        for (int ks = 0; ks < 6; ++ks) {
            bf16x8 af[4], bfr[3];
#pragma unroll
            for (int nt = 0; nt < 3; ++nt)
                bfr[nt] = *(const bf16x8*)(bp + (size_t)nt*3072 + ks*512);
#pragma unroll
            for (int mt = 0; mt < 4; ++mt)
                af[mt] = *(const bf16x8*)&At[mt*16 + lr][ks*32 + lg*8];
#pragma unroll
            for (int mt = 0; mt < 4; ++mt)
#pragma unroll
                for (int nt = 0; nt < 3; ++nt)
                    acc[mt][nt] = __builtin_amdgcn_mfma_f32_16x16x32_bf16(
                        af[mt], bfr[nt], acc[mt][nt], 0, 0, 0);
        }
        __syncthreads();                     // prior St readers done
#pragma unroll
        for (int mt = 0; mt < 4; ++mt)
#pragma unroll
            for (int nt = 0; nt < 3; ++nt)
#pragma unroll
                for (int reg = 0; reg < 4; ++reg)
                    St[mt*16 + lg*4 + reg][(w*3 + nt)*16 + lr] = f2b(acc[mt][nt][reg]);
        __syncthreads();
        // head-separated coalesced store: pair = h*64 + r; wave writes 3KB runs
#pragma unroll
        for (int pp = 0; pp < 2; ++pp) {
            const int pair = t + pp*256;
            const int h = pair >> 6, r = pair & 63;
            u16* dst = yb + (size_t)h*PS + (p0 + r)*DH;
#pragma unroll
            for (int j8 = 0; j8 < 3; ++j8)
                *(u16x8*)(dst + j8*8) = *(const u16x8*)&St[r][h*24 + j8*8];
        }
    }
}

// ---------------------------------------------------------------------------
// K4: out-projection MFMA GEMM. A = attn output, head-sep [h][p][24] (L3-hot;
// 8|24 so every 8-elem k-chunk stays inside one head plane). fp32 output
// staged via LDS -> fully contiguous 4KB-per-instruction NHWC stores.
// ---------------------------------------------------------------------------
__global__ __launch_bounds__(256) void outproj_gemm(
    const u16* __restrict__ a, const u16* __restrict__ bpack, float* __restrict__ yf)
{
    __shared__ __align__(16) float St[64][196];  // 50,176 B (784B stride: bank-step 4)
    const int t = threadIdx.x, l = t & 63, w = t >> 6;
    const int lr = l & 15, lg = l >> 4;
    const size_t p0 = (size_t)blockIdx.x * 64;

    f32x4 acc[4][3];
#pragma unroll
    for (int mt = 0; mt < 4; ++mt)
#pragma unroll
        for (int nt = 0; nt < 3; ++nt) acc[mt][nt] = (f32x4){0.f,0.f,0.f,0.f};
    const u16* bp = bpack + (size_t)3*36864 + (size_t)w*3*3072 + l*8;
#pragma unroll
    for (int ks = 0; ks < 6; ++ks) {
        const int ch0 = ks*32 + lg*8;
        const int hh = ch0 / 24, cc = ch0 - hh*24;
        const u16* ap = a + (size_t)hh*PS + (p0 + lr)*DH + cc;
        bf16x8 af[4], bfr[3];
#pragma unroll
        for (int nt = 0; nt < 3; ++nt)
            bfr[nt] = *(const bf16x8*)(bp + (size_t)nt*3072 + ks*512);
#pragma unroll
        for (int mt = 0; mt < 4; ++mt)
            af[mt] = *(const bf16x8*)(ap + (size_t)mt*16*DH);
#pragma unroll
        for (int mt = 0; mt < 4; ++mt)
#pragma unroll
            for (int nt = 0; nt < 3; ++nt)
                acc[mt][nt] = __builtin_amdgcn_mfma_f32_16x16x32_bf16(
                    af[mt], bfr[nt], acc[mt][nt], 0, 0, 0);
    }
#pragma unroll
    for (int mt = 0; mt < 4; ++mt)
#pragma unroll
        for (int nt = 0; nt < 3; ++nt)
#pragma unroll
            for (int reg = 0; reg < 4; ++reg)
                St[mt*16 + lg*4 + reg][(w*3 + nt)*16 + lr] = acc[mt][nt][reg];
    __syncthreads();
#pragma unroll
    for (int i = 0; i < 12; ++i) {
        const int f = t + i*256;             // over 64 rows x 48 float4
        const int row = f / 48, c4 = f - row*48;
        *(float4*)(yf + (p0 + row)*CH + c4*4) = *(const float4*)&St[row][c4*4];
    }
}

// ---------------------------------------------------------------------------
// K2: 3x3 depthwise conv per head-plane [h][b][y][x][24], bf16, fp32 accum.
// ---------------------------------------------------------------------------
__global__ __launch_bounds__(256) void dwconv_kernel(
    const u16* __restrict__ in, const float* __restrict__ wdw, u16* __restrict__ out)
{
    __shared__ float wloc[DH*9];          // this head's weights [c][tap]
    const int t = threadIdx.x;
    const int h = blockIdx.y;
    if (t < DH*9) wloc[t] = wdw[h*DH*9 + t];
    __syncthreads();
    const int gid2 = blockIdx.x * 256 + t;   // in [0, NPOS*3)
    const int p  = gid2 / 3, c8 = gid2 - p*3;
    const int x = p & 255, y = (p >> 8) & 255, b = p >> 16;
    const size_t plane = (size_t)h * PS;
    float acc[8] = {0,0,0,0,0,0,0,0};
#pragma unroll
    for (int ky = 0; ky < 3; ++ky) {
        const int yy = y + ky - 1;
        if (yy < 0 || yy >= NHH) continue;
#pragma unroll
        for (int kx = 0; kx < 3; ++kx) {
            const int xx = x + kx - 1;
            if (xx < 0 || xx >= NWW) continue;
            const u16x8 iv = *(const u16x8*)(in + plane + (size_t)((b*NHH + yy)*NWW + xx)*DH + c8*8);
#pragma unroll
            for (int j = 0; j < 8; ++j)
                acc[j] += b2f(iv[j]) * wloc[(c8*8 + j)*9 + ky*3 + kx];
        }
    }
    u16x8 ov;
#pragma unroll
    for (int j = 0; j < 8; ++j) ov[j] = f2b(acc[j]);
    *(u16x8*)(out + plane + (size_t)p*DH + c8*8) = ov;
}

// ---------------------------------------------------------------------------
// K3: per-(window, head) channel attention; head-separated I/O.
// ---------------------------------------------------------------------------
__global__ __launch_bounds__(256) void attn_kernel(
    const u16* __restrict__ q, const u16* __restrict__ k, const u16* __restrict__ v,
    const float* __restrict__ rescale, u16* __restrict__ out)
{
    __shared__ float qt[DH][260];
    __shared__ float kt[DH][260];
    float* pbuf = &kt[0][0];            // reused: partials[4*576] + sim/attn[576]
    const int t    = threadIdx.x;
    const int widx = blockIdx.x;        // b*256 + wy*16 + wx
    const int h    = blockIdx.y;
    const int b  = widx >> 8;
    const int wy = (widx >> 4) & 15, wx = widx & 15;
    const int n  = t;
    const int gy = wy*WIN + (n >> 4), gx = wx*WIN + (n & 15);
    const size_t pbase = (size_t)h*PS + (size_t)((b*NHH + gy)*NWW + gx) * DH;

    // phase A: q,k transposed into LDS (fp32)
#pragma unroll
    for (int j8 = 0; j8 < 3; ++j8) {
        const u16x8 qv = *(const u16x8*)(q + pbase + j8*8);
        const u16x8 kv = *(const u16x8*)(k + pbase + j8*8);
#pragma unroll
        for (int j = 0; j < 8; ++j) { qt[j8*8+j][n] = b2f(qv[j]); kt[j8*8+j][n] = b2f(kv[j]); }
    }
    __syncthreads();

    // phase B: sim partials; wave covers 64 of n, thread = 3x3 (i,j) block
    const int wvi  = t >> 6;
    const int lane = t & 63;
    const int i0 = (lane >> 3) * 3, j0 = (lane & 7) * 3;
    float s[3][3];
#pragma unroll
    for (int a2 = 0; a2 < 3; ++a2)
#pragma unroll
        for (int c = 0; c < 3; ++c) s[a2][c] = 0.f;
    for (int nn = wvi*64; nn < wvi*64 + 64; nn += 4) {
        float4 qv[3], kv[3];
#pragma unroll
        for (int a2 = 0; a2 < 3; ++a2) {
            qv[a2] = *(const float4*)&qt[i0+a2][nn];
            kv[a2] = *(const float4*)&kt[j0+a2][nn];
        }
#pragma unroll
        for (int a2 = 0; a2 < 3; ++a2)
#pragma unroll
            for (int c = 0; c < 3; ++c)
                s[a2][c] += qv[a2].x*kv[c].x + qv[a2].y*kv[c].y + qv[a2].z*kv[c].z + qv[a2].w*kv[c].w;
    }
    __syncthreads();

    // phase C: partials -> kt-flat; v -> qt
#pragma unroll
    for (int a2 = 0; a2 < 3; ++a2)
#pragma unroll
        for (int c = 0; c < 3; ++c)
            pbuf[wvi*576 + (i0+a2)*24 + (j0+c)] = s[a2][c];
#pragma unroll
    for (int j8 = 0; j8 < 3; ++j8) {
        const u16x8 vv = *(const u16x8*)(v + pbase + j8*8);
#pragma unroll
        for (int j = 0; j < 8; ++j) qt[j8*8+j][n] = b2f(vv[j]);
    }
    __syncthreads();

    // phase D: reduce 4 wave-partials + rescale
    const float rsc = rescale[h];
    for (int e = t; e < 576; e += 256) {
        const float sum = pbuf[e] + pbuf[576+e] + pbuf[1152+e] + pbuf[1728+e];
        pbuf[2304 + e] = sum * rsc;
    }
    __syncthreads();

    // phase E: softmax over j per row i
    if (t < 24) {
        float* srow = pbuf + 2304 + t*24;
        float m = srow[0];
#pragma unroll
        for (int j = 1; j < 24; ++j) m = fmaxf(m, srow[j]);
        float ssum = 0.f;
#pragma unroll
        for (int j = 0; j < 24; ++j) { const float e_ = expf(srow[j] - m); srow[j] = e_; ssum += e_; }
        const float inv = 1.f / ssum;
#pragma unroll
        for (int j = 0; j < 24; ++j) srow[j] *= inv;
    }
    __syncthreads();

    // phase F: PV — thread (iw,nc): 6 i-rows x one 4-wide n-chunk
    const int nc = t & 63;
    const int ib = (t >> 6) * 6;
    float4 acc[6];
#pragma unroll
    for (int ii = 0; ii < 6; ++ii) acc[ii] = make_float4(0.f,0.f,0.f,0.f);
#pragma unroll
    for (int j = 0; j < 24; ++j) {
        const float4 vj = *(const float4*)&qt[j][nc*4];
        const float aw0 = pbuf[2304 + (ib+0)*24 + j];
        const float aw1 = pbuf[2304 + (ib+1)*24 + j];
        const float aw2 = pbuf[2304 + (ib+2)*24 + j];
        const float aw3 = pbuf[2304 + (ib+3)*24 + j];
        const float aw4 = pbuf[2304 + (ib+4)*24 + j];
        const float aw5 = pbuf[2304 + (ib+5)*24 + j];
        acc[0].x += aw0*vj.x; acc[0].y += aw0*vj.y; acc[0].z += aw0*vj.z; acc[0].w += aw0*vj.w;
        acc[1].x += aw1*vj.x; acc[1].y += aw1*vj.y; acc[1].z += aw1*vj.z; acc[1].w += aw1*vj.w;
        acc[2].x += aw2*vj.x; acc[2].y += aw2*vj.y; acc[2].z += aw2*vj.z; acc[2].w += aw2*vj.w;
        acc[3].x += aw3*vj.x; acc[3].y += aw3*vj.y; acc[3].z += aw3*vj.z; acc[3].w += aw3*vj.w;
        acc[4].x += aw4*vj.x; acc[4].y += aw4*vj.y; acc[4].z += aw4*vj.z; acc[4].w += aw4*vj.w;
        acc[5].x += aw5*vj.x; acc[5].y += aw5*vj.y; acc[5].z += aw5*vj.z; acc[5].w += aw5*vj.w;
    }
    __syncthreads();
    // phase G: stage output fp32 into qt
#pragma unroll
    for (int ii = 0; ii < 6; ++ii)
        *(float4*)&qt[ib+ii][nc*4] = acc[ii];
    __syncthreads();
    // phase H: coalesced bf16 store (3KB contiguous per 64-lane wave)
#pragma unroll
    for (int j8 = 0; j8 < 3; ++j8) {
        u16x8 o;
#pragma unroll
        for (int j = 0; j < 8; ++j) o[j] = f2b(qt[j8*8+j][n]);
        *(u16x8*)(out + pbase + j8*8) = o;
    }
}

// ---------------------------------------------------------------------------
extern "C" void kernel_launch(void* const* d_in, const int* in_sizes, int n_in,
                              void* d_out, int out_size, void* d_ws, size_t ws_size,
                              hipStream_t stream)
{
    (void)in_sizes; (void)n_in; (void)out_size; (void)ws_size;
    const float* x     = (const float*)d_in[0];
    const float* ln_g  = (const float*)d_in[1];
    const float* ln_b  = (const float*)d_in[2];
    const float* wq1   = (const float*)d_in[3];
    const float* wq2   = (const float*)d_in[4];
    const float* wk1   = (const float*)d_in[5];
    const float* wk2   = (const float*)d_in[6];
    const float* wv1   = (const float*)d_in[7];
    const float* wv2   = (const float*)d_in[8];
    const float* rsc   = (const float*)d_in[9];
    const float* w_out = (const float*)d_in[10];
    float* out = (float*)d_out;

    const size_t NT = (size_t)NPOS * CH;    // 50,331,648 elems
    u16* u0 = (u16*)d_ws;                   // (unused this round; keep offsets)
    u16* u1 = u0 + NT;                      // head-sep tensors
    u16* u2 = u1 + NT;
    u16* u3 = u2 + NT;
    u16* u4 = u3 + NT;
    u16* pack = u4 + NT;                    // 147,456 u16

    prep_weights<<<72, 256, 0, stream>>>(wq1, wk1, wv1, w_out, pack);
    // fused LN + QKV GEMM -> head-separated q,k,v
    ln_qkv_gemm<<<NPOS/64, 256, 0, stream>>>(x, ln_g, ln_b, pack, u1, u2, u3);
    // depthwise 3x3 per head-plane:  q:u1->u4   k:u2->u1   v:u3->u2
    dwconv_kernel<<<dim3(NPOS*3/256, HEADS), 256, 0, stream>>>(u1, wq2, u4);
    dwconv_kernel<<<dim3(NPOS*3/256, HEADS), 256, 0, stream>>>(u2, wk2, u1);
    dwconv_kernel<<<dim3(NPOS*3/256, HEADS), 256, 0, stream>>>(u3, wv2, u2);
    // windowed channel attention: q=u4, k=u1, v=u2 -> u3 (head-sep)
    attn_kernel<<<dim3(NB*256, HEADS), 256, 0, stream>>>(u4, u1, u2, rsc, u3);
    // output projection (A head-sep, fp32 NHWC out)
    outproj_gemm<<<NPOS/64, 256, 0, stream>>>(u3, pack, out);
}